// Round 1
// baseline (4394.349 us; speedup 1.0000x reference)
//
#include <hip/hip_runtime.h>
#include <cstdio>

typedef unsigned short u16;
typedef __attribute__((ext_vector_type(8))) short bf16x8;   // 8 x bf16 (4 VGPRs)
typedef __attribute__((ext_vector_type(4))) float f32x4;

__device__ inline u16 f2bf(float x) {
  union { float f; unsigned u; } v; v.f = x;
  unsigned r = v.u + 0x7FFFu + ((v.u >> 16) & 1u);   // RNE
  return (u16)(r >> 16);
}
__device__ inline float sigm(float x) { return 1.0f / (1.0f + __expf(-x)); }
__device__ inline float tanh_fast(float x) { return 1.0f - 2.0f / (__expf(2.0f * x) + 1.0f); }

// ---------------- fp32 -> bf16 convert (vectorized) ----------------
__global__ __launch_bounds__(256) void k_convert(const float* __restrict__ in,
                                                 u16* __restrict__ out, int n4) {
  int i = blockIdx.x * blockDim.x + threadIdx.x;
  int stride = gridDim.x * blockDim.x;
  const float4* in4 = (const float4*)in;
  ushort4* out4 = (ushort4*)out;
  for (; i < n4; i += stride) {
    float4 v = in4[i];
    ushort4 o; o.x = f2bf(v.x); o.y = f2bf(v.y); o.z = f2bf(v.z); o.w = f2bf(v.w);
    out4[i] = o;
  }
}

// h0 -> h_bf buffer 0 (bf16), zero barrier counter
__global__ __launch_bounds__(256) void k_init_h(const float* __restrict__ h0,
                                                u16* __restrict__ h_bf,
                                                unsigned* __restrict__ cnt) {
  int i = blockIdx.x * blockDim.x + threadIdx.x;
  if (i == 0) *cnt = 0u;
  if (i < 32768) h_bf[i] = f2bf(h0[i]);
}

// [R][C] fp32 -> [C][R] bf16 (tiled transpose)
__global__ __launch_bounds__(256) void k_transpose(const float* __restrict__ in,
                                                   u16* __restrict__ out, int R, int C) {
  __shared__ u16 tile[32][33];
  int tx = threadIdx.x & 31, ty = threadIdx.x >> 5;
  int c = blockIdx.x * 32 + tx;
  for (int i = 0; i < 32; i += 8) {
    int r = blockIdx.y * 32 + ty + i;
    tile[ty + i][tx] = f2bf(in[(size_t)r * C + c]);
  }
  __syncthreads();
  int r = blockIdx.y * 32 + tx;
  for (int i = 0; i < 32; i += 8) {
    int cc = blockIdx.x * 32 + ty + i;
    out[(size_t)cc * R + r] = tile[tx][ty + i];
  }
}

// ---------------- bf16 MFMA GEMM: C[M][N] = A[M][K] * BT[N][K]^T + bias ----------------
// 128x128 tile, BK=32, 256 threads (2x2 waves of 64x64), fp32 accumulate.
__global__ __launch_bounds__(256) void k_gemm_bt(const u16* __restrict__ A,
                                                 const u16* __restrict__ BT,
                                                 const float* __restrict__ bias,
                                                 float* __restrict__ C,
                                                 int M, int N, int K) {
  __shared__ u16 As[128][40];   // +8 pad: 2-way max bank aliasing on b128 reads
  __shared__ u16 Bs[128][40];
  const int m0 = blockIdx.y * 128, n0 = blockIdx.x * 128;
  const int tid = threadIdx.x;
  const int lane = tid & 63, wave = tid >> 6;
  const int wm = (wave >> 1) * 64, wn = (wave & 1) * 64;
  const int lm = lane & 15, quad = lane >> 4;
  const int r = tid >> 1, kh = (tid & 1) * 16;   // each thread stages 16 bf16 of one row

  f32x4 acc[4][4];
  for (int i = 0; i < 4; i++)
    for (int j = 0; j < 4; j++) acc[i][j] = (f32x4){0.f, 0.f, 0.f, 0.f};

  for (int k0 = 0; k0 < K; k0 += 32) {
    const uint4* ap = (const uint4*)(A + (size_t)(m0 + r) * K + k0 + kh);
    uint4 av0 = ap[0], av1 = ap[1];
    const uint4* bp = (const uint4*)(BT + (size_t)(n0 + r) * K + k0 + kh);
    uint4 bv0 = bp[0], bv1 = bp[1];
    __syncthreads();
    *(uint4*)&As[r][kh] = av0; *(uint4*)&As[r][kh + 8] = av1;
    *(uint4*)&Bs[r][kh] = bv0; *(uint4*)&Bs[r][kh + 8] = bv1;
    __syncthreads();
    bf16x8 a_frag[4], b_frag[4];
    for (int i = 0; i < 4; i++) a_frag[i] = *(const bf16x8*)&As[wm + i * 16 + lm][quad * 8];
    for (int j = 0; j < 4; j++) b_frag[j] = *(const bf16x8*)&Bs[wn + j * 16 + lm][quad * 8];
    for (int i = 0; i < 4; i++)
      for (int j = 0; j < 4; j++)
        acc[i][j] = __builtin_amdgcn_mfma_f32_16x16x32_bf16(a_frag[i], b_frag[j], acc[i][j], 0, 0, 0);
  }
  // C/D layout: col = lane&15, row = quad*4 + reg  [verified m89/m91]
  for (int i = 0; i < 4; i++)
    for (int j = 0; j < 4; j++) {
      int row = m0 + wm + i * 16 + quad * 4;
      int col = n0 + wn + j * 16 + lm;
      float bc = bias[col];
      for (int rr = 0; rr < 4; rr++)
        C[(size_t)(row + rr) * N + col] = acc[i][j][rr] + bc;
    }
}

// ---------------- persistent LSTM scan ----------------
// 64 WGs x 256 thr. WG g owns h-columns jglob in [16g,16g+16) across the 4 gates
// (packed col pc = gate*16 + jl). Whs slice resident in LDS for all 256 steps.
#define NWG 64

__device__ inline void grid_barrier(unsigned* cnt, unsigned target) {
  __syncthreads();
  if (threadIdx.x == 0) {
    __threadfence();  // release: flush this XCD's L2 (h_bf writes) toward LLC
    __hip_atomic_fetch_add(cnt, 1u, __ATOMIC_RELEASE, __HIP_MEMORY_SCOPE_AGENT);
    while (__hip_atomic_load(cnt, __ATOMIC_ACQUIRE, __HIP_MEMORY_SCOPE_AGENT) < target)
      __builtin_amdgcn_s_sleep(2);
  }
  __syncthreads();
  __threadfence();  // acquire: invalidate stale L1/L2 before reading peers' h
}

__global__ __launch_bounds__(256) void k_lstm(const float* __restrict__ Z,    // [8192][4096]
                                              const u16* __restrict__ WhT,    // [4096][1024]
                                              const float* __restrict__ c0,   // [32][1024]
                                              u16* __restrict__ h_bf,         // [2][32][1024]
                                              u16* __restrict__ Hs,           // [8192][1024]
                                              float* __restrict__ out_c,
                                              float* __restrict__ out_h,
                                              unsigned* __restrict__ cnt) {
  __shared__ u16 Whs[64][1032];      // 64 packed cols x K=1024 (+8 pad) = 132 KB
  __shared__ float z_buf[32][66];    // [b][pc] (+2 pad -> quads hit distinct banks)
  __shared__ float c_buf[32][16];    // fp32 cell state, private to this WG
  const int g = blockIdx.x;
  const int tid = threadIdx.x;
  const int lane = tid & 63, wave = tid >> 6;
  const int lm = lane & 15, quad = lane >> 4;

  // stage Wh^T slice: packed row pc -> WhT row (pc>>4)*1024 + 16g + (pc&15)
  for (int pc = 0; pc < 64; pc++) {
    int grow = (pc >> 4) * 1024 + 16 * g + (pc & 15);
    ushort4 v = *(const ushort4*)(WhT + (size_t)grow * 1024 + tid * 4);
    *(ushort4*)&Whs[pc][tid * 4] = v;
  }
  for (int p = tid; p < 512; p += 256) {
    int b = p >> 4, jl = p & 15;
    c_buf[b][jl] = c0[b * 1024 + 16 * g + jl];
  }
  __syncthreads();

  for (int t = 0; t < 256; t++) {
    // prefetch this step's Z (x@Wi+b) contributions into registers (hides HBM latency)
    float zp[2][4];
    for (int pi = 0; pi < 2; pi++) {
      int p = tid + pi * 256;
      int b = p >> 4, jl = p & 15;
      size_t zrow = ((size_t)b * 256 + t) * 4096 + 16 * g + jl;
      zp[pi][0] = Z[zrow];
      zp[pi][1] = Z[zrow + 1024];
      zp[pi][2] = Z[zrow + 2048];
      zp[pi][3] = Z[zrow + 3072];
    }

    // h_t @ Wh_slice : wave w computes packed cols [16w,16w+16), full K=1024
    const u16* hsrc = h_bf + (t & 1) * 32768;
    f32x4 acc0 = (f32x4){0.f, 0.f, 0.f, 0.f};
    f32x4 acc1 = (f32x4){0.f, 0.f, 0.f, 0.f};
#pragma unroll 4
    for (int ks = 0; ks < 32; ks++) {
      bf16x8 bfr = *(const bf16x8*)&Whs[wave * 16 + lm][ks * 32 + quad * 8];
      bf16x8 a0 = *(const bf16x8*)(hsrc + (size_t)lm * 1024 + ks * 32 + quad * 8);
      bf16x8 a1 = *(const bf16x8*)(hsrc + (size_t)(16 + lm) * 1024 + ks * 32 + quad * 8);
      acc0 = __builtin_amdgcn_mfma_f32_16x16x32_bf16(a0, bfr, acc0, 0, 0, 0);
      acc1 = __builtin_amdgcn_mfma_f32_16x16x32_bf16(a1, bfr, acc1, 0, 0, 0);
    }
    for (int rr = 0; rr < 4; rr++) {
      z_buf[quad * 4 + rr][wave * 16 + lm] = acc0[rr];
      z_buf[16 + quad * 4 + rr][wave * 16 + lm] = acc1[rr];
    }
    __syncthreads();

    // gate math: thread handles (b, jl) pairs p=tid, tid+256
    for (int pi = 0; pi < 2; pi++) {
      int p = tid + pi * 256;
      int b = p >> 4, jl = p & 15;
      float zi = z_buf[b][jl] + zp[pi][0];
      float zf = z_buf[b][16 + jl] + zp[pi][1];
      float zg = z_buf[b][32 + jl] + zp[pi][2];
      float zo = z_buf[b][48 + jl] + zp[pi][3];
      float ig = sigm(zi), fg = sigm(zf), gg = tanh_fast(zg), og = sigm(zo);
      float cn = fg * c_buf[b][jl] + ig * gg;
      float hn = og * tanh_fast(cn);
      c_buf[b][jl] = cn;
      u16 hb = f2bf(hn);
      h_bf[((t + 1) & 1) * 32768 + b * 1024 + 16 * g + jl] = hb;
      Hs[((size_t)b * 256 + t) * 1024 + 16 * g + jl] = hb;
      if (t == 255) {
        out_c[b * 1024 + 16 * g + jl] = cn;
        out_h[b * 1024 + 16 * g + jl] = hn;
      }
    }
    if (t != 255) grid_barrier(cnt, (unsigned)(NWG * (t + 1)));
  }
}

extern "C" void kernel_launch(void* const* d_in, const int* in_sizes, int n_in,
                              void* d_out, int out_size, void* d_ws, size_t ws_size,
                              hipStream_t stream) {
  const float* c0   = (const float*)d_in[0];
  const float* h0   = (const float*)d_in[1];
  const float* X    = (const float*)d_in[2];   // [32,256,1024] == [8192][1024]
  const float* Wi   = (const float*)d_in[3];   // [1024][4096]
  const float* Wh   = (const float*)d_in[4];   // [1024][4096]
  const float* bias = (const float*)d_in[5];   // [4096]
  const float* Wd   = (const float*)d_in[6];   // [1024][1024]
  const float* bd   = (const float*)d_in[7];   // [1024]
  float* out   = (float*)d_out;
  float* out_c = out;
  float* out_h = out + 32768;
  float* out_x = out + 65536;

  char* ws = (char*)d_ws;
  size_t off = 0;
  auto alloc = [&](size_t bytes) { char* p = ws + off; off += (bytes + 255) & ~255ull; return p; };
  float*    Z    = (float*)alloc(134217728ull);   // [8192][4096] fp32
  u16*      Xb   = (u16*)alloc(16777216ull);      // [8192][1024] bf16
  u16*      WiT  = (u16*)alloc(8388608ull);       // [4096][1024] bf16
  u16*      WhT  = (u16*)alloc(8388608ull);       // [4096][1024] bf16
  u16*      WdT  = (u16*)alloc(2097152ull);       // [1024][1024] bf16
  u16*      Hs   = (u16*)alloc(16777216ull);      // [8192][1024] bf16
  u16*      h_bf = (u16*)alloc(131072ull);        // [2][32][1024] bf16
  unsigned* cnt  = (unsigned*)alloc(256);
  if (off > ws_size) {
    fprintf(stderr, "WS too small: need %zu have %zu\n", off, ws_size);
    return;
  }

  k_convert<<<2048, 256, 0, stream>>>(X, Xb, 8388608 / 4);
  k_init_h<<<128, 256, 0, stream>>>(h0, h_bf, cnt);
  k_transpose<<<dim3(128, 32), 256, 0, stream>>>(Wi, WiT, 1024, 4096);
  k_transpose<<<dim3(128, 32), 256, 0, stream>>>(Wh, WhT, 1024, 4096);
  k_transpose<<<dim3(32, 32), 256, 0, stream>>>(Wd, WdT, 1024, 1024);
  k_gemm_bt<<<dim3(32, 64), 256, 0, stream>>>(Xb, WiT, bias, Z, 8192, 4096, 1024);
  k_lstm<<<NWG, 256, 0, stream>>>(Z, WhT, c0, h_bf, Hs, out_c, out_h, cnt);
  k_gemm_bt<<<dim3(8, 64), 256, 0, stream>>>(Hs, WdT, bd, out_x, 8192, 1024, 1024);
}

// Round 2
// 2814.201 us; speedup vs baseline: 1.5615x; 1.5615x over previous
//
#include <hip/hip_runtime.h>
#include <cstdio>

typedef unsigned short u16;
typedef unsigned int u32;
typedef __attribute__((ext_vector_type(8))) short bf16x8;   // 8 x bf16 (4 VGPRs)
typedef __attribute__((ext_vector_type(4))) float f32x4;

#define NWG 64
#define FLAG_STRIDE 32   // u32s -> 128 B between flags (own cacheline each)

__device__ inline u16 f2bf(float x) {
  union { float f; unsigned u; } v; v.f = x;
  unsigned r = v.u + 0x7FFFu + ((v.u >> 16) & 1u);   // RNE
  return (u16)(r >> 16);
}
__device__ inline float sigm(float x) { return 1.0f / (1.0f + __expf(-x)); }
__device__ inline float tanh_fast(float x) { return 1.0f - 2.0f / (__expf(2.0f * x) + 1.0f); }

// ---------------- fp32 -> bf16 convert (vectorized) ----------------
__global__ __launch_bounds__(256) void k_convert(const float* __restrict__ in,
                                                 u16* __restrict__ out, int n4) {
  int i = blockIdx.x * blockDim.x + threadIdx.x;
  int stride = gridDim.x * blockDim.x;
  const float4* in4 = (const float4*)in;
  ushort4* out4 = (ushort4*)out;
  for (; i < n4; i += stride) {
    float4 v = in4[i];
    ushort4 o; o.x = f2bf(v.x); o.y = f2bf(v.y); o.z = f2bf(v.z); o.w = f2bf(v.w);
    out4[i] = o;
  }
}

// h0 -> h_bf buffer 0 (bf16), zero the 64 per-WG flags
__global__ __launch_bounds__(256) void k_init_h(const float* __restrict__ h0,
                                                u16* __restrict__ h_bf,
                                                u32* __restrict__ flags) {
  int i = blockIdx.x * blockDim.x + threadIdx.x;
  if (i < NWG * FLAG_STRIDE) flags[i] = 0u;
  if (i < 32768) h_bf[i] = f2bf(h0[i]);
}

// [R][C] fp32 -> [C][R] bf16 (tiled transpose)
__global__ __launch_bounds__(256) void k_transpose(const float* __restrict__ in,
                                                   u16* __restrict__ out, int R, int C) {
  __shared__ u16 tile[32][33];
  int tx = threadIdx.x & 31, ty = threadIdx.x >> 5;
  int c = blockIdx.x * 32 + tx;
  for (int i = 0; i < 32; i += 8) {
    int r = blockIdx.y * 32 + ty + i;
    tile[ty + i][tx] = f2bf(in[(size_t)r * C + c]);
  }
  __syncthreads();
  int r = blockIdx.y * 32 + tx;
  for (int i = 0; i < 32; i += 8) {
    int cc = blockIdx.x * 32 + ty + i;
    out[(size_t)cc * R + r] = tile[tx][ty + i];
  }
}

// ---------------- bf16 MFMA GEMM: C[M][N] = A[M][K] * BT[N][K]^T + bias ----------------
__global__ __launch_bounds__(256) void k_gemm_bt(const u16* __restrict__ A,
                                                 const u16* __restrict__ BT,
                                                 const float* __restrict__ bias,
                                                 float* __restrict__ C,
                                                 int M, int N, int K) {
  __shared__ u16 As[128][40];
  __shared__ u16 Bs[128][40];
  const int m0 = blockIdx.y * 128, n0 = blockIdx.x * 128;
  const int tid = threadIdx.x;
  const int lane = tid & 63, wave = tid >> 6;
  const int wm = (wave >> 1) * 64, wn = (wave & 1) * 64;
  const int lm = lane & 15, quad = lane >> 4;
  const int r = tid >> 1, kh = (tid & 1) * 16;

  f32x4 acc[4][4];
  for (int i = 0; i < 4; i++)
    for (int j = 0; j < 4; j++) acc[i][j] = (f32x4){0.f, 0.f, 0.f, 0.f};

  for (int k0 = 0; k0 < K; k0 += 32) {
    const uint4* ap = (const uint4*)(A + (size_t)(m0 + r) * K + k0 + kh);
    uint4 av0 = ap[0], av1 = ap[1];
    const uint4* bp = (const uint4*)(BT + (size_t)(n0 + r) * K + k0 + kh);
    uint4 bv0 = bp[0], bv1 = bp[1];
    __syncthreads();
    *(uint4*)&As[r][kh] = av0; *(uint4*)&As[r][kh + 8] = av1;
    *(uint4*)&Bs[r][kh] = bv0; *(uint4*)&Bs[r][kh + 8] = bv1;
    __syncthreads();
    bf16x8 a_frag[4], b_frag[4];
    for (int i = 0; i < 4; i++) a_frag[i] = *(const bf16x8*)&As[wm + i * 16 + lm][quad * 8];
    for (int j = 0; j < 4; j++) b_frag[j] = *(const bf16x8*)&Bs[wn + j * 16 + lm][quad * 8];
    for (int i = 0; i < 4; i++)
      for (int j = 0; j < 4; j++)
        acc[i][j] = __builtin_amdgcn_mfma_f32_16x16x32_bf16(a_frag[i], b_frag[j], acc[i][j], 0, 0, 0);
  }
  for (int i = 0; i < 4; i++)
    for (int j = 0; j < 4; j++) {
      int row = m0 + wm + i * 16 + quad * 4;
      int col = n0 + wn + j * 16 + lm;
      float bc = bias[col];
      for (int rr = 0; rr < 4; rr++)
        C[(size_t)(row + rr) * N + col] = acc[i][j][rr] + bc;
    }
}

// ---------------- persistent LSTM scan ----------------
// 64 WGs x 256 thr. WG g owns h-columns [16g,16g+16) across the 4 gates.
// Sync per step: write-through (sc0sc1) h stores -> syncthreads (vmcnt0) ->
// per-WG flag store; consumers poll 64 flags in wave0, one acquire inv, barrier.
__global__ __launch_bounds__(256) void k_lstm(const float* __restrict__ Z,    // [8192][4096]
                                              const u16* __restrict__ WhT,    // [4096][1024]
                                              const float* __restrict__ c0,   // [32][1024]
                                              u32* __restrict__ h_bf,         // [2][32][512] u32 (2 bf16 each)
                                              u32* __restrict__ HsU,          // [8192][512] u32
                                              float* __restrict__ out_c,
                                              float* __restrict__ out_h,
                                              u32* __restrict__ flags) {
  __shared__ u16 Whs[64][1032];      // 64 packed cols x K=1024 (+8 pad) = 132 KB
  __shared__ float z_buf[32][66];    // [batch][packed col]
  const int g = blockIdx.x;
  const int tid = threadIdx.x;
  const int lane = tid & 63, wave = tid >> 6;
  const int lm = lane & 15, quad = lane >> 4;
  const int b = tid >> 3, jlp = tid & 7, jl0 = 2 * jlp;   // gate-phase ownership

  // stage Wh^T slice: packed row pc -> WhT row (pc>>4)*1024 + 16g + (pc&15)
  for (int pc = 0; pc < 64; pc++) {
    int grow = (pc >> 4) * 1024 + 16 * g + (pc & 15);
    ushort4 v = *(const ushort4*)(WhT + (size_t)grow * 1024 + tid * 4);
    *(ushort4*)&Whs[pc][tid * 4] = v;
  }
  // cell state in registers: this thread owns (b, cols 16g+jl0, +1)
  float2 creg = *(const float2*)(c0 + b * 1024 + 16 * g + jl0);
  float c_0 = creg.x, c_1 = creg.y;
  __syncthreads();

  const u16* wrow = &Whs[wave * 16 + lm][quad * 8];

  for (int t = 0; t < 256; t++) {
    // 1. prefetch this step's Z contributions (overlaps the flag poll)
    size_t zrow = ((size_t)b * 256 + t) * 4096 + 16 * g + jl0;
    const float2* zr = (const float2*)(Z + zrow);
    float2 zp_i = zr[0], zp_f = zr[512], zp_g = zr[1024], zp_o = zr[1536];

    // 2. wave0 waits until every WG has published h_t, then one acquire inv
    if (wave == 0) {
      const u32 tgt = (u32)t;
      u32* fp = flags + lane * FLAG_STRIDE;  // lane<64 == WG index
      while (true) {
        u32 v = __hip_atomic_load(fp, __ATOMIC_RELAXED, __HIP_MEMORY_SCOPE_AGENT);
        if (__all((int)(v >= tgt))) break;
        __builtin_amdgcn_s_sleep(1);
      }
      __builtin_amdgcn_fence(__ATOMIC_ACQUIRE, "agent");  // invalidate stale L1/L2
    }
    __syncthreads();  // A: orders all waves' h loads after the inv

    // 3. h_t @ Wh_slice (4 independent MFMA chains for dep-latency ILP)
    const u16* hsrc = (const u16*)(h_bf + (size_t)(t & 1) * 16384);
    const u16* h0r = hsrc + (size_t)lm * 1024 + quad * 8;
    const u16* h1r = hsrc + (size_t)(lm + 16) * 1024 + quad * 8;
    f32x4 p0a = (f32x4){0.f,0.f,0.f,0.f}, p0b = p0a, p1a = p0a, p1b = p0a;
#pragma unroll 4
    for (int ks = 0; ks < 16; ks++) {
      bf16x8 wA  = *(const bf16x8*)(wrow + ks * 32);
      bf16x8 wB  = *(const bf16x8*)(wrow + (ks + 16) * 32);
      bf16x8 a0A = *(const bf16x8*)(h0r + ks * 32);
      bf16x8 a1A = *(const bf16x8*)(h1r + ks * 32);
      bf16x8 a0B = *(const bf16x8*)(h0r + (ks + 16) * 32);
      bf16x8 a1B = *(const bf16x8*)(h1r + (ks + 16) * 32);
      p0a = __builtin_amdgcn_mfma_f32_16x16x32_bf16(a0A, wA, p0a, 0, 0, 0);
      p1a = __builtin_amdgcn_mfma_f32_16x16x32_bf16(a1A, wA, p1a, 0, 0, 0);
      p0b = __builtin_amdgcn_mfma_f32_16x16x32_bf16(a0B, wB, p0b, 0, 0, 0);
      p1b = __builtin_amdgcn_mfma_f32_16x16x32_bf16(a1B, wB, p1b, 0, 0, 0);
    }
    f32x4 acc0 = p0a + p0b, acc1 = p1a + p1b;
    for (int rr = 0; rr < 4; rr++) {
      z_buf[quad * 4 + rr][wave * 16 + lm] = acc0[rr];
      z_buf[16 + quad * 4 + rr][wave * 16 + lm] = acc1[rr];
    }
    __syncthreads();  // B: z_buf ready for gate phase

    // 4. gate math (2 columns per thread), h published write-through to LLC
    float zi0 = z_buf[b][jl0]      + zp_i.x, zi1 = z_buf[b][jl0 + 1]  + zp_i.y;
    float zf0 = z_buf[b][16 + jl0] + zp_f.x, zf1 = z_buf[b][17 + jl0] + zp_f.y;
    float zg0 = z_buf[b][32 + jl0] + zp_g.x, zg1 = z_buf[b][33 + jl0] + zp_g.y;
    float zo0 = z_buf[b][48 + jl0] + zp_o.x, zo1 = z_buf[b][49 + jl0] + zp_o.y;
    float i0 = sigm(zi0), f0 = sigm(zf0), g0v = tanh_fast(zg0), o0 = sigm(zo0);
    float i1 = sigm(zi1), f1 = sigm(zf1), g1v = tanh_fast(zg1), o1 = sigm(zo1);
    c_0 = f0 * c_0 + i0 * g0v;
    c_1 = f1 * c_1 + i1 * g1v;
    float h0v = o0 * tanh_fast(c_0);
    float h1v = o1 * tanh_fast(c_1);
    u32 hword = (u32)f2bf(h0v) | ((u32)f2bf(h1v) << 16);
    // write-through (sc0 sc1): completes at the coherence point, no wbl2 needed
    __hip_atomic_store(h_bf + (size_t)((t + 1) & 1) * 16384 + b * 512 + 8 * g + jlp,
                       hword, __ATOMIC_RELAXED, __HIP_MEMORY_SCOPE_AGENT);
    __syncthreads();  // C: vmcnt(0) per thread -> all h stores globally visible

    // 5. publish flag; Hs / final outputs off the critical path
    if (tid == 0)
      __hip_atomic_store(flags + g * FLAG_STRIDE, (u32)(t + 1),
                         __ATOMIC_RELAXED, __HIP_MEMORY_SCOPE_AGENT);
    __builtin_nontemporal_store(hword, HsU + ((size_t)b * 256 + t) * 512 + 8 * g + jlp);
    if (t == 255) {
      int o = b * 1024 + 16 * g + jl0;
      *(float2*)(out_c + o) = make_float2(c_0, c_1);
      *(float2*)(out_h + o) = make_float2(h0v, h1v);
    }
  }
}

extern "C" void kernel_launch(void* const* d_in, const int* in_sizes, int n_in,
                              void* d_out, int out_size, void* d_ws, size_t ws_size,
                              hipStream_t stream) {
  const float* c0   = (const float*)d_in[0];
  const float* h0   = (const float*)d_in[1];
  const float* X    = (const float*)d_in[2];   // [32,256,1024]
  const float* Wi   = (const float*)d_in[3];   // [1024][4096]
  const float* Wh   = (const float*)d_in[4];   // [1024][4096]
  const float* bias = (const float*)d_in[5];   // [4096]
  const float* Wd   = (const float*)d_in[6];   // [1024][1024]
  const float* bd   = (const float*)d_in[7];   // [1024]
  float* out   = (float*)d_out;
  float* out_c = out;
  float* out_h = out + 32768;
  float* out_x = out + 65536;

  char* ws = (char*)d_ws;
  size_t off = 0;
  auto alloc = [&](size_t bytes) { char* p = ws + off; off += (bytes + 255) & ~255ull; return p; };
  float* Z     = (float*)alloc(134217728ull);   // [8192][4096] fp32
  u16*   Xb    = (u16*)alloc(16777216ull);      // [8192][1024] bf16
  u16*   WiT   = (u16*)alloc(8388608ull);       // [4096][1024] bf16
  u16*   WhT   = (u16*)alloc(8388608ull);       // [4096][1024] bf16
  u16*   WdT   = (u16*)alloc(2097152ull);       // [1024][1024] bf16
  u16*   Hs    = (u16*)alloc(16777216ull);      // [8192][1024] bf16
  u32*   h_bf  = (u32*)alloc(131072ull);        // [2][32][512] u32
  u32*   flags = (u32*)alloc(NWG * FLAG_STRIDE * 4);
  if (off > ws_size) {
    fprintf(stderr, "WS too small: need %zu have %zu\n", off, ws_size);
    return;
  }

  k_convert<<<2048, 256, 0, stream>>>(X, Xb, 8388608 / 4);
  k_init_h<<<128, 256, 0, stream>>>(h0, (u16*)h_bf, flags);
  k_transpose<<<dim3(128, 32), 256, 0, stream>>>(Wi, WiT, 1024, 4096);
  k_transpose<<<dim3(128, 32), 256, 0, stream>>>(Wh, WhT, 1024, 4096);
  k_transpose<<<dim3(32, 32), 256, 0, stream>>>(Wd, WdT, 1024, 1024);
  k_gemm_bt<<<dim3(32, 64), 256, 0, stream>>>(Xb, WiT, bias, Z, 8192, 4096, 1024);
  k_lstm<<<NWG, 256, 0, stream>>>(Z, WhT, c0, h_bf, (u32*)Hs, out_c, out_h, flags);
  k_gemm_bt<<<dim3(8, 64), 256, 0, stream>>>(Hs, WdT, bd, out_x, 8192, 1024, 1024);
}

// Round 3
// 1178.192 us; speedup vs baseline: 3.7297x; 2.3886x over previous
//
#include <hip/hip_runtime.h>
#include <cstdio>

typedef unsigned short u16;
typedef unsigned int u32;
typedef unsigned long long u64;
typedef __attribute__((ext_vector_type(8))) short bf16x8;   // 8 x bf16 (4 VGPRs)
typedef __attribute__((ext_vector_type(4))) float f32x4;

#define NWG 128
#define FLAG_STRIDE 32   // u32s -> 128 B between flags (own cacheline each)

__device__ inline u16 f2bf(float x) {
  union { float f; unsigned u; } v; v.f = x;
  unsigned r = v.u + 0x7FFFu + ((v.u >> 16) & 1u);   // RNE
  return (u16)(r >> 16);
}
__device__ inline float sigm(float x) { return 1.0f / (1.0f + __expf(-x)); }
__device__ inline float tanh_fast(float x) { return 1.0f - 2.0f / (__expf(2.0f * x) + 1.0f); }

// ---------------- fp32 -> bf16 convert (vectorized) ----------------
__global__ __launch_bounds__(256) void k_convert(const float* __restrict__ in,
                                                 u16* __restrict__ out, int n4) {
  int i = blockIdx.x * blockDim.x + threadIdx.x;
  int stride = gridDim.x * blockDim.x;
  const float4* in4 = (const float4*)in;
  ushort4* out4 = (ushort4*)out;
  for (; i < n4; i += stride) {
    float4 v = in4[i];
    ushort4 o; o.x = f2bf(v.x); o.y = f2bf(v.y); o.z = f2bf(v.z); o.w = f2bf(v.w);
    out4[i] = o;
  }
}

// h0 -> h_bf buffer 0 (bf16), zero the per-WG flags
__global__ __launch_bounds__(256) void k_init_h(const float* __restrict__ h0,
                                                u16* __restrict__ h_bf,
                                                u32* __restrict__ flags) {
  int i = blockIdx.x * blockDim.x + threadIdx.x;
  if (i < NWG * FLAG_STRIDE) flags[i] = 0u;
  if (i < 32768) h_bf[i] = f2bf(h0[i]);
}

// [R][C] fp32 -> [C][R] bf16 (tiled transpose)
__global__ __launch_bounds__(256) void k_transpose(const float* __restrict__ in,
                                                   u16* __restrict__ out, int R, int C) {
  __shared__ u16 tile[32][33];
  int tx = threadIdx.x & 31, ty = threadIdx.x >> 5;
  int c = blockIdx.x * 32 + tx;
  for (int i = 0; i < 32; i += 8) {
    int r = blockIdx.y * 32 + ty + i;
    tile[ty + i][tx] = f2bf(in[(size_t)r * C + c]);
  }
  __syncthreads();
  int r = blockIdx.y * 32 + tx;
  for (int i = 0; i < 32; i += 8) {
    int cc = blockIdx.x * 32 + ty + i;
    out[(size_t)cc * R + r] = tile[tx][ty + i];
  }
}

// ---------------- bf16 MFMA GEMM: C[M][N] = A[M][K] * BT[N][K]^T + bias ----------------
__global__ __launch_bounds__(256) void k_gemm_bt(const u16* __restrict__ A,
                                                 const u16* __restrict__ BT,
                                                 const float* __restrict__ bias,
                                                 float* __restrict__ C,
                                                 int M, int N, int K) {
  __shared__ u16 As[128][40];
  __shared__ u16 Bs[128][40];
  const int m0 = blockIdx.y * 128, n0 = blockIdx.x * 128;
  const int tid = threadIdx.x;
  const int lane = tid & 63, wave = tid >> 6;
  const int wm = (wave >> 1) * 64, wn = (wave & 1) * 64;
  const int lm = lane & 15, quad = lane >> 4;
  const int r = tid >> 1, kh = (tid & 1) * 16;

  f32x4 acc[4][4];
  for (int i = 0; i < 4; i++)
    for (int j = 0; j < 4; j++) acc[i][j] = (f32x4){0.f, 0.f, 0.f, 0.f};

  for (int k0 = 0; k0 < K; k0 += 32) {
    const uint4* ap = (const uint4*)(A + (size_t)(m0 + r) * K + k0 + kh);
    uint4 av0 = ap[0], av1 = ap[1];
    const uint4* bp = (const uint4*)(BT + (size_t)(n0 + r) * K + k0 + kh);
    uint4 bv0 = bp[0], bv1 = bp[1];
    __syncthreads();
    *(uint4*)&As[r][kh] = av0; *(uint4*)&As[r][kh + 8] = av1;
    *(uint4*)&Bs[r][kh] = bv0; *(uint4*)&Bs[r][kh + 8] = bv1;
    __syncthreads();
    bf16x8 a_frag[4], b_frag[4];
    for (int i = 0; i < 4; i++) a_frag[i] = *(const bf16x8*)&As[wm + i * 16 + lm][quad * 8];
    for (int j = 0; j < 4; j++) b_frag[j] = *(const bf16x8*)&Bs[wn + j * 16 + lm][quad * 8];
    for (int i = 0; i < 4; i++)
      for (int j = 0; j < 4; j++)
        acc[i][j] = __builtin_amdgcn_mfma_f32_16x16x32_bf16(a_frag[i], b_frag[j], acc[i][j], 0, 0, 0);
  }
  for (int i = 0; i < 4; i++)
    for (int j = 0; j < 4; j++) {
      int row = m0 + wm + i * 16 + quad * 4;
      int col = n0 + wn + j * 16 + lm;
      float bc = bias[col];
      for (int rr = 0; rr < 4; rr++)
        C[(size_t)(row + rr) * N + col] = acc[i][j][rr] + bc;
    }
}

// ---------------- persistent LSTM scan ----------------
// 128 WGs x 256 thr (1/CU). WG g owns h-cols [8g,8g+8) x 4 gates (32 packed cols).
// NO fences: h + flags move via device-coherent (sc0sc1) accesses only; L2 never
// invalidated, so Z stays cached. h staged to LDS once per step per WG.
__global__ __launch_bounds__(256) void k_lstm(const float* __restrict__ Z,    // [8192][4096]
                                              const u16* __restrict__ WhT,    // [4096][1024]
                                              const float* __restrict__ c0,   // [32][1024]
                                              u16* __restrict__ h_bf,         // [2][32][1024] bf16
                                              u16* __restrict__ Hs,           // [8192][1024] bf16
                                              float* __restrict__ out_c,
                                              float* __restrict__ out_h,
                                              u32* __restrict__ flags) {
  __shared__ u16 Whs[32][1032];      // 32 packed cols x K=1024 (+8 pad) = 66 KB
  __shared__ u16 h_lds[32][1032];    // h_t staged, 66 KB
  __shared__ float z_buf[32][34];    // [batch][packed col]
  const int g = blockIdx.x;
  const int tid = threadIdx.x;
  const int lane = tid & 63, wave = tid >> 6;
  const int lm = lane & 15, quad = lane >> 4;
  const int mhalf = wave >> 1, ntile = wave & 1;
  const int b = tid >> 3, jl = tid & 7;

  // stage Wh^T slice: packed col pc -> WhT row (pc>>3)*1024 + 8g + (pc&7)
  {
    int pc = tid >> 3, seg = tid & 7;
    int grow = (pc >> 3) * 1024 + 8 * g + (pc & 7);
    const uint4* src = (const uint4*)(WhT + (size_t)grow * 1024 + seg * 128);
#pragma unroll
    for (int i = 0; i < 16; i++) {
      uint4 v = src[i];
      *(uint4*)&Whs[pc][seg * 128 + i * 8] = v;
    }
  }
  float creg = c0[b * 1024 + 8 * g + jl];   // this thread owns (b, col 8g+jl)

  for (int t = 0; t < 256; t++) {
    // 1. prefetch this step's Z contributions (L2/L3-cached; overlaps the poll)
    size_t zbase = ((size_t)b * 256 + t) * 4096 + 8 * g + jl;
    float z_i = Z[zbase], z_f = Z[zbase + 1024], z_g = Z[zbase + 2048], z_o = Z[zbase + 3072];

    // 2. all waves poll all 128 flags (2 per lane), coherent relaxed loads
    {
      const u32 tgt = (u32)t;
      const u32* f0 = flags + lane * FLAG_STRIDE;
      const u32* f1 = flags + (lane + 64) * FLAG_STRIDE;
      while (true) {
        u32 v0 = __hip_atomic_load(f0, __ATOMIC_RELAXED, __HIP_MEMORY_SCOPE_AGENT);
        u32 v1 = __hip_atomic_load(f1, __ATOMIC_RELAXED, __HIP_MEMORY_SCOPE_AGENT);
        if (__all((v0 >= tgt) && (v1 >= tgt))) break;
        __builtin_amdgcn_s_sleep(1);
      }
      asm volatile("" ::: "memory");  // no hoisting of h loads above the poll
    }

    // 3. stage h_t -> LDS: 32 coherent u64 loads/thread, fully preloaded
    {
      const u64* hq = (const u64*)(h_bf + (size_t)(t & 1) * 32768);
      u64 v[32];
#pragma unroll
      for (int i = 0; i < 32; i++)
        v[i] = __hip_atomic_load(hq + i * 256 + tid, __ATOMIC_RELAXED, __HIP_MEMORY_SCOPE_AGENT);
#pragma unroll
      for (int i = 0; i < 32; i++) {
        int q = i * 256 + tid;
        *(u64*)&h_lds[q >> 8][(q & 255) * 4] = v[i];
      }
    }
    __syncthreads();  // B1: h_lds (and, on t=0, Whs) ready

    // 4. MFMA: wave (mhalf,ntile) computes 16x16 block, K=1024, 4 ILP chains
    const u16* arow = &h_lds[mhalf * 16 + lm][quad * 8];
    const u16* brow = &Whs[ntile * 16 + lm][quad * 8];
    f32x4 a0 = (f32x4){0.f, 0.f, 0.f, 0.f}, a1 = a0, a2 = a0, a3 = a0;
#pragma unroll
    for (int ks = 0; ks < 32; ks += 4) {
      bf16x8 af0 = *(const bf16x8*)(arow + (ks + 0) * 32);
      bf16x8 bf0 = *(const bf16x8*)(brow + (ks + 0) * 32);
      bf16x8 af1 = *(const bf16x8*)(arow + (ks + 1) * 32);
      bf16x8 bf1 = *(const bf16x8*)(brow + (ks + 1) * 32);
      bf16x8 af2 = *(const bf16x8*)(arow + (ks + 2) * 32);
      bf16x8 bf2 = *(const bf16x8*)(brow + (ks + 2) * 32);
      bf16x8 af3 = *(const bf16x8*)(arow + (ks + 3) * 32);
      bf16x8 bf3 = *(const bf16x8*)(brow + (ks + 3) * 32);
      a0 = __builtin_amdgcn_mfma_f32_16x16x32_bf16(af0, bf0, a0, 0, 0, 0);
      a1 = __builtin_amdgcn_mfma_f32_16x16x32_bf16(af1, bf1, a1, 0, 0, 0);
      a2 = __builtin_amdgcn_mfma_f32_16x16x32_bf16(af2, bf2, a2, 0, 0, 0);
      a3 = __builtin_amdgcn_mfma_f32_16x16x32_bf16(af3, bf3, a3, 0, 0, 0);
    }
    f32x4 accs = (a0 + a1) + (a2 + a3);
    for (int rr = 0; rr < 4; rr++)
      z_buf[mhalf * 16 + quad * 4 + rr][ntile * 16 + lm] = accs[rr];
    __syncthreads();  // B2: z_buf ready

    // 5. gate math: one (b, col) per thread
    float zi = z_buf[b][jl]      + z_i;
    float zf = z_buf[b][8 + jl]  + z_f;
    float zg = z_buf[b][16 + jl] + z_g;
    float zo = z_buf[b][24 + jl] + z_o;
    float ig = sigm(zi), fg = sigm(zf), gg = tanh_fast(zg), og = sigm(zo);
    creg = fg * creg + ig * gg;
    float hv = og * tanh_fast(creg);
    u16 hb = f2bf(hv);
    // publish h write-through to the coherence point (no L2 residency)
    __hip_atomic_store(h_bf + (size_t)((t + 1) & 1) * 32768 + b * 1024 + 8 * g + jl,
                       hb, __ATOMIC_RELAXED, __HIP_MEMORY_SCOPE_AGENT);
    __builtin_nontemporal_store(hb, Hs + ((size_t)b * 256 + t) * 1024 + 8 * g + jl);
    if (t == 255) {
      out_c[b * 1024 + 8 * g + jl] = creg;
      out_h[b * 1024 + 8 * g + jl] = hv;
    }
    __syncthreads();  // B3: per-thread vmcnt drain -> all h stores at LLC
    if (tid == 0)
      __hip_atomic_store(flags + g * FLAG_STRIDE, (u32)(t + 1),
                         __ATOMIC_RELAXED, __HIP_MEMORY_SCOPE_AGENT);
  }
}

extern "C" void kernel_launch(void* const* d_in, const int* in_sizes, int n_in,
                              void* d_out, int out_size, void* d_ws, size_t ws_size,
                              hipStream_t stream) {
  const float* c0   = (const float*)d_in[0];
  const float* h0   = (const float*)d_in[1];
  const float* X    = (const float*)d_in[2];   // [32,256,1024]
  const float* Wi   = (const float*)d_in[3];   // [1024][4096]
  const float* Wh   = (const float*)d_in[4];   // [1024][4096]
  const float* bias = (const float*)d_in[5];   // [4096]
  const float* Wd   = (const float*)d_in[6];   // [1024][1024]
  const float* bd   = (const float*)d_in[7];   // [1024]
  float* out   = (float*)d_out;
  float* out_c = out;
  float* out_h = out + 32768;
  float* out_x = out + 65536;

  char* ws = (char*)d_ws;
  size_t off = 0;
  auto alloc = [&](size_t bytes) { char* p = ws + off; off += (bytes + 255) & ~255ull; return p; };
  float* Z     = (float*)alloc(134217728ull);   // [8192][4096] fp32
  u16*   Xb    = (u16*)alloc(16777216ull);      // [8192][1024] bf16
  u16*   WiT   = (u16*)alloc(8388608ull);       // [4096][1024] bf16
  u16*   WhT   = (u16*)alloc(8388608ull);       // [4096][1024] bf16
  u16*   WdT   = (u16*)alloc(2097152ull);       // [1024][1024] bf16
  u16*   Hs    = (u16*)alloc(16777216ull);      // [8192][1024] bf16
  u16*   h_bf  = (u16*)alloc(131072ull);        // [2][32][1024] bf16
  u32*   flags = (u32*)alloc(NWG * FLAG_STRIDE * 4);
  if (off > ws_size) {
    fprintf(stderr, "WS too small: need %zu have %zu\n", off, ws_size);
    return;
  }

  k_convert<<<2048, 256, 0, stream>>>(X, Xb, 8388608 / 4);
  k_init_h<<<128, 256, 0, stream>>>(h0, h_bf, flags);
  k_transpose<<<dim3(128, 32), 256, 0, stream>>>(Wi, WiT, 1024, 4096);
  k_transpose<<<dim3(128, 32), 256, 0, stream>>>(Wh, WhT, 1024, 4096);
  k_transpose<<<dim3(32, 32), 256, 0, stream>>>(Wd, WdT, 1024, 1024);
  k_gemm_bt<<<dim3(32, 64), 256, 0, stream>>>(Xb, WiT, bias, Z, 8192, 4096, 1024);
  k_lstm<<<NWG, 256, 0, stream>>>(Z, WhT, c0, h_bf, Hs, out_c, out_h, flags);
  k_gemm_bt<<<dim3(8, 64), 256, 0, stream>>>(Hs, WdT, bd, out_x, 8192, 1024, 1024);
}